// Round 8
// baseline (495.099 us; speedup 1.0000x reference)
//
#include <hip/hip_runtime.h>
#include <math.h>

#define NNODES 50000
#define FIN 768
#define HDIM 128
#define NEDGE 400000
#define NSB 49  // ceil(50000/1024)

typedef _Float16 half8 __attribute__((ext_vector_type(8)));
typedef _Float16 half4 __attribute__((ext_vector_type(4)));
typedef _Float16 half2v __attribute__((ext_vector_type(2)));
typedef float f32x4 __attribute__((ext_vector_type(4)));

__device__ __forceinline__ void gld_lds16(const void* g, void* l) {
    __builtin_amdgcn_global_load_lds((const __attribute__((address_space(1))) unsigned int*)g,
                                     (__attribute__((address_space(3))) unsigned int*)l, 16, 0, 0);
}

// convert 8 f32 (optionally gelu) -> half8, store to LDS
template<bool GELU>
__device__ __forceinline__ void cvt_store(_Float16* dst, f32x4 v0, f32x4 v1) {
    float tmp[8] = {v0[0], v0[1], v0[2], v0[3], v1[0], v1[1], v1[2], v1[3]};
    half8 av;
    #pragma unroll
    for (int j = 0; j < 8; ++j) {
        float x = tmp[j];
        if (GELU) x = 0.5f * x * (1.0f + erff(x * 0.70710678118654752f));
        av[j] = (_Float16)x;
    }
    *(half8*)dst = av;
}

// ---------------- CSR build ----------------

__global__ __launch_bounds__(256) void count2_kernel(const int* __restrict__ ei0, const int* __restrict__ ei1,
                                                     int* __restrict__ deg0, int* __restrict__ deg1) {
    int e = blockIdx.x * 256 + threadIdx.x;
    const int* ei = blockIdx.y ? ei1 : ei0;
    int* deg = blockIdx.y ? deg1 : deg0;
    if (e < NEDGE) atomicAdd(&deg[ei[NEDGE + e]], 1);
}

// phase 1: per-block exclusive scan, block sums out
__global__ __launch_bounds__(1024) void scan1_kernel(const int* __restrict__ deg0, const int* __restrict__ deg1,
                                                     int* __restrict__ ptr0, int* __restrict__ ptr1,
                                                     int* __restrict__ sums) {
    const int r = blockIdx.y;
    const int* deg = r ? deg1 : deg0;
    int* ptr = r ? ptr1 : ptr0;
    const int b = blockIdx.x, t = threadIdx.x, i = b * 1024 + t;
    __shared__ int buf[1024];
    int v = (i < NNODES) ? deg[i] : 0;
    buf[t] = v;
    __syncthreads();
    for (int off = 1; off < 1024; off <<= 1) {
        int x = (t >= off) ? buf[t - off] : 0;
        __syncthreads();
        buf[t] += x;
        __syncthreads();
    }
    if (i < NNODES) ptr[i] = buf[t] - v;          // local exclusive
    if (t == 1023) sums[r * 64 + b] = buf[1023];  // block total
}

// phase 2: wave-scan the NSB block sums -> exclusive offsets; write grand total to ptr[NNODES]
__global__ __launch_bounds__(64) void scan2_kernel(int* __restrict__ sums,
                                                   int* __restrict__ ptr0, int* __restrict__ ptr1) {
    const int r = blockIdx.x, t = threadIdx.x;
    int orig = (t < NSB) ? sums[r * 64 + t] : 0;
    int v = orig;
    #pragma unroll
    for (int off = 1; off < 64; off <<= 1) {
        int u = __shfl_up(v, off, 64);
        if (t >= off) v += u;
    }
    if (t < NSB) sums[r * 64 + t] = v - orig;     // exclusive
    if (t == NSB - 1) (r ? ptr1 : ptr0)[NNODES] = v;
}

// phase 3: add block offsets
__global__ __launch_bounds__(1024) void scan3_kernel(const int* __restrict__ sums,
                                                     int* __restrict__ ptr0, int* __restrict__ ptr1) {
    const int r = blockIdx.y;
    int* ptr = r ? ptr1 : ptr0;
    const int i = blockIdx.x * 1024 + threadIdx.x;
    if (i < NNODES) ptr[i] += sums[r * 64 + blockIdx.x];
}

__global__ __launch_bounds__(256) void scatter2_kernel(const int* __restrict__ ei0, const int* __restrict__ ei1,
                                                       const int* __restrict__ ptr0, const int* __restrict__ ptr1,
                                                       int* __restrict__ fill0, int* __restrict__ fill1,
                                                       int* __restrict__ csr0, int* __restrict__ csr1) {
    int e = blockIdx.x * 256 + threadIdx.x;
    const int* ei = blockIdx.y ? ei1 : ei0;
    const int* ptr = blockIdx.y ? ptr1 : ptr0;
    int* fill = blockIdx.y ? fill1 : fill0;
    int* csr = blockIdx.y ? csr1 : csr0;
    if (e < NEDGE) {
        int s = ei[e], d = ei[NEDGE + e];
        int p = atomicAdd(&fill[d], 1);
        csr[ptr[d] + p] = s;
    }
}

// ---------------- batched 128x128x128 f32 weight combines (z: 0=WkA0 1=WvM0 2=WkA1 3=WvM1) ----------------
__global__ __launch_bounds__(256) void gemm_cmb_kernel(
    const float* __restrict__ Wk, const float* __restrict__ Wv,
    const float* __restrict__ A0v, const float* __restrict__ M0v,
    const float* __restrict__ A1v, const float* __restrict__ M1v,
    float* __restrict__ WkA0, float* __restrict__ WvM0,
    float* __restrict__ WkA1, float* __restrict__ WvM1)
{
    const int z = blockIdx.z;
    const float* A = (z & 1) ? Wv : Wk;
    const float* B = (z == 0) ? A0v : (z == 1) ? M0v : (z == 2) ? A1v : M1v;
    float* C = (z == 0) ? WkA0 : (z == 1) ? WvM0 : (z == 2) ? WkA1 : WvM1;
    const int M = 128, N = 128, K = 128;
    __shared__ float As[16][64];
    __shared__ float Bs[16][64];
    const int t = threadIdx.x;
    const int tx = t & 15, ty = t >> 4;
    const int bm = blockIdx.x * 64, bn = blockIdx.y * 64;
    const int ar = t >> 2, ac = (t & 3) << 2;
    const int br = t >> 4, bc = (t & 15) << 2;
    float acc[4][4] = {};
    for (int kb = 0; kb < K; kb += 16) {
        float4 av = *reinterpret_cast<const float4*>(A + (size_t)(bm + ar) * K + kb + ac);
        float4 bv = *reinterpret_cast<const float4*>(B + (size_t)(kb + br) * N + bn + bc);
        __syncthreads();
        As[ac + 0][ar] = av.x; As[ac + 1][ar] = av.y; As[ac + 2][ar] = av.z; As[ac + 3][ar] = av.w;
        *reinterpret_cast<float4*>(&Bs[br][bc]) = bv;
        __syncthreads();
        #pragma unroll
        for (int kk = 0; kk < 16; ++kk) {
            float4 a = *reinterpret_cast<const float4*>(&As[kk][ty << 2]);
            float4 b = *reinterpret_cast<const float4*>(&Bs[kk][tx << 2]);
            float am[4] = {a.x, a.y, a.z, a.w};
            float bb[4] = {b.x, b.y, b.z, b.w};
            #pragma unroll
            for (int i = 0; i < 4; ++i)
                #pragma unroll
                for (int j = 0; j < 4; ++j)
                    acc[i][j] = fmaf(am[i], bb[j], acc[i][j]);
        }
    }
    #pragma unroll
    for (int i = 0; i < 4; ++i)
        #pragma unroll
        for (int j = 0; j < 4; ++j)
            C[(size_t)(bm + (ty << 2) + i) * N + bn + (tx << 2) + j] = acc[i][j];
}

// batched bias combines, written directly into permuted bqkv positions (z: 0=kA0 1=vM0 2=kA1 3=vM1)
__global__ __launch_bounds__(128) void bias_cmb_kernel(
    const float* __restrict__ bk, const float* __restrict__ bv,
    const float* __restrict__ A0v, const float* __restrict__ M0v,
    const float* __restrict__ A1v, const float* __restrict__ M1v,
    float* __restrict__ bqkv)
{
    const int z = blockIdx.x;
    const int j = threadIdx.x;
    const float* b = (z & 1) ? bv : bk;
    const float* Mtx = (z == 0) ? A0v : (z == 1) ? M0v : (z == 2) ? A1v : M1v;
    float s = 0.f;
    for (int i = 0; i < HDIM; ++i) s += b[i] * Mtx[i * HDIM + j];
    const int r = z >> 1, kv = z & 1;
    bqkv[128 + r * 256 + ((j >> 1) << 2) + (kv << 1) + (j & 1)] = s;
}

// ---------------- weight packing ----------------
// qkv row layout: [q: 0..127][rel0: 128..383 as quads k2j,k2j+1,v2j,v2j+1][rel1: 384..639 same]
__global__ __launch_bounds__(128) void pack_qkvT(
    const float* __restrict__ Wq,   const float* __restrict__ WkA0, const float* __restrict__ WvM0,
    const float* __restrict__ WkA1, const float* __restrict__ WvM1,
    const float* __restrict__ bq,
    _Float16* __restrict__ WT, float* __restrict__ bb)
{
    int n = blockIdx.x;      // (seg, col) enumeration, 0..639
    int k = threadIdx.x;     // 0..127
    int seg = n >> 7, col = n & 127;
    const float* W = (seg == 0) ? Wq : (seg == 1) ? WkA0 : (seg == 2) ? WvM0 : (seg == 3) ? WkA1 : WvM1;
    int np;
    if (seg == 0) np = col;
    else {
        int r = (seg - 1) >> 1, kv = (seg - 1) & 1;
        np = 128 + r * 256 + ((col >> 1) << 2) + (kv << 1) + (col & 1);
    }
    WT[(size_t)np * 128 + k] = (_Float16)W[(size_t)k * 128 + col];
    if (seg == 0 && k == 0) bb[col] = bq[col];
}

// WT[n][k] = W[k][n], fp16
__global__ void transpose_h(const float* __restrict__ W, _Float16* __restrict__ WT, int K, int N) {
    int n = blockIdx.x, k = threadIdx.x;
    WT[(size_t)n * K + k] = (_Float16)W[(size_t)k * N + n];
}

// ---------------- fp16 MFMA GEMM (BM=128, BN=128, BK=32, 2-phase double-buffered) ----------------
// MODE 0: +bias; MODE 1: leaky; MODE 2: skip-mix with Dh (fp16 [M,128])
template<int MODE, bool A_F32, bool GELU>
__global__ __launch_bounds__(256) void gemm_h(
    const void* __restrict__ Av, const _Float16* __restrict__ Bt,
    const float* __restrict__ bias, const _Float16* __restrict__ Dh,
    const float* __restrict__ gate, _Float16* __restrict__ C,
    int M, int N, int K)
{
    __shared__ _Float16 sA[2][4096]; // per buf: 8 frags * 64 lanes * 8 fp16
    __shared__ _Float16 sB[2][4096];
    const int tid = threadIdx.x;
    const int w = tid >> 6, lane = tid & 63;
    const int wm = w >> 1, wn = w & 1;
    const int bm = blockIdx.x * 128, bn = blockIdx.y * 128;

    // staging coordinates, chunks it=0 (c=tid) and it=1 (c=256+tid)
    int arow0, arow1, brow0, brow1, kc0, kc1, cb0, cb1, c0, c1;
    {
        const int c = tid, l = c & 63;
        const int row = ((c >> 6) << 4) | (l & 15);
        kc0 = (l >> 4) << 3; cb0 = (tid & 192); c0 = c;
        arow0 = bm + row; if (arow0 > M - 1) arow0 = M - 1;
        brow0 = bn + row; if (brow0 > N - 1) brow0 = N - 1;
    }
    {
        const int c = 256 + tid, l = c & 63;
        const int row = ((c >> 6) << 4) | (l & 15);
        kc1 = (l >> 4) << 3; cb1 = 256 + (tid & 192); c1 = c;
        arow1 = bm + row; if (arow1 > M - 1) arow1 = M - 1;
        brow1 = bn + row; if (brow1 > N - 1) brow1 = N - 1;
    }

    const f32x4 zero = {0.f, 0.f, 0.f, 0.f};
    f32x4 acc[4][4];
    #pragma unroll
    for (int i = 0; i < 4; ++i)
        #pragma unroll
        for (int j = 0; j < 4; ++j) acc[i][j] = zero;

    const int nt = K >> 5;
    f32x4 pa00, pa01, pa10, pa11;

    // ---- prologue: stage tile 0 into buf 0 ----
    if (A_F32) {
        const float* a0 = (const float*)Av + (size_t)arow0 * K + kc0;
        pa00 = *(const f32x4*)a0; pa01 = *(const f32x4*)(a0 + 4);
        const float* a1 = (const float*)Av + (size_t)arow1 * K + kc1;
        pa10 = *(const f32x4*)a1; pa11 = *(const f32x4*)(a1 + 4);
    } else {
        gld_lds16((const _Float16*)Av + (size_t)arow0 * K + kc0, sA[0] + (size_t)cb0 * 8);
        gld_lds16((const _Float16*)Av + (size_t)arow1 * K + kc1, sA[0] + (size_t)cb1 * 8);
    }
    gld_lds16(Bt + (size_t)brow0 * K + kc0, sB[0] + (size_t)cb0 * 8);
    gld_lds16(Bt + (size_t)brow1 * K + kc1, sB[0] + (size_t)cb1 * 8);
    if (A_F32) {
        cvt_store<GELU>(sA[0] + (size_t)c0 * 8, pa00, pa01);
        cvt_store<GELU>(sA[0] + (size_t)c1 * 8, pa10, pa11);
    }
    __syncthreads();

    int buf = 0;
    for (int t = 0; t < nt; ++t) {
        const int nxt = buf ^ 1;
        const bool more = (t + 1) < nt;
        if (more) {
            const int kb = (t + 1) << 5;
            if (A_F32) {
                const float* a0 = (const float*)Av + (size_t)arow0 * K + kb + kc0;
                pa00 = *(const f32x4*)a0; pa01 = *(const f32x4*)(a0 + 4);
                const float* a1 = (const float*)Av + (size_t)arow1 * K + kb + kc1;
                pa10 = *(const f32x4*)a1; pa11 = *(const f32x4*)(a1 + 4);
            } else {
                gld_lds16((const _Float16*)Av + (size_t)arow0 * K + kb + kc0, sA[nxt] + (size_t)cb0 * 8);
                gld_lds16((const _Float16*)Av + (size_t)arow1 * K + kb + kc1, sA[nxt] + (size_t)cb1 * 8);
            }
            gld_lds16(Bt + (size_t)brow0 * K + kb + kc0, sB[nxt] + (size_t)cb0 * 8);
            gld_lds16(Bt + (size_t)brow1 * K + kb + kc1, sB[nxt] + (size_t)cb1 * 8);
        }
        half8 af[4], bf[4];
        #pragma unroll
        for (int i = 0; i < 4; ++i) af[i] = *(const half8*)(sA[buf] + ((size_t)((wm * 4 + i) * 64 + lane)) * 8);
        #pragma unroll
        for (int i = 0; i < 4; ++i) bf[i] = *(const half8*)(sB[buf] + ((size_t)((wn * 4 + i) * 64 + lane)) * 8);
        #pragma unroll
        for (int i = 0; i < 4; ++i)
            #pragma unroll
            for (int j = 0; j < 4; ++j)
                acc[i][j] = __builtin_amdgcn_mfma_f32_16x16x32_f16(af[i], bf[j], acc[i][j], 0, 0, 0);
        if (more && A_F32) {
            cvt_store<GELU>(sA[nxt] + (size_t)c0 * 8, pa00, pa01);
            cvt_store<GELU>(sA[nxt] + (size_t)c1 * 8, pa10, pa11);
        }
        __syncthreads();
        buf = nxt;
    }

    float be = 0.f;
    if (MODE == 2) be = 1.0f / (1.0f + __expf(-gate[0]));
    const int crow0 = bm + wm * 64;
    const int ccol0 = bn + wn * 64;
    #pragma unroll
    for (int i = 0; i < 4; ++i) {
        #pragma unroll
        for (int j = 0; j < 4; ++j) {
            const int col = ccol0 + j * 16 + (lane & 15);
            if (col >= N) continue;
            #pragma unroll
            for (int r = 0; r < 4; ++r) {
                const int row = crow0 + i * 16 + ((lane >> 4) << 2) + r;
                if (row >= M) continue;
                float val = acc[i][j][r] + bias[col];
                if (MODE == 1) val = (val >= 0.f) ? val : 0.01f * val;
                if (MODE == 2) val = be * val + (1.f - be) * (float)Dh[(size_t)row * HDIM + col];
                C[(size_t)row * N + col] = (_Float16)val;
            }
        }
    }
}

// ---------------- fp16 MFMA GEMM (BM=32, BN=128, BK=64, 2-phase double-buffered) ----------------
// wave w owns output cols [w*32, w*32+32)
template<int MODE, bool A_F32, bool GELU>
__global__ __launch_bounds__(256) void gemm_h32(
    const void* __restrict__ Av, const _Float16* __restrict__ Bt,
    const float* __restrict__ bias, const _Float16* __restrict__ Dh,
    const float* __restrict__ gate, _Float16* __restrict__ C,
    int M, int N, int K)
{
    __shared__ _Float16 sA[2][4 * 64 * 8];   // per buf: 4 frags (2m x 2k), 4KB
    __shared__ _Float16 sB[2][16 * 64 * 8];  // per buf: 16 frags (4w x 2n x 2k), 16KB
    const int tid = threadIdx.x;
    const int w = tid >> 6, lane = tid & 63;
    const int rl = lane & 15, kg = lane >> 4;
    const int bm = blockIdx.x * 32;
    const f32x4 zero = {0.f, 0.f, 0.f, 0.f};
    f32x4 acc[2][2] = {{zero, zero}, {zero, zero}};

    const int mi = w >> 1, kkA = w & 1;
    int arow = bm + mi * 16 + rl; if (arow > M - 1) arow = M - 1;
    const int koA = kkA * 32 + kg * 8;
    int nrowB[4];
    #pragma unroll
    for (int j = 0; j < 4; ++j) {
        const int ni = (j >> 1) & 1;
        int nr = w * 32 + ni * 16 + rl; if (nr > N - 1) nr = N - 1;
        nrowB[j] = nr;
    }

    const int nt = K >> 6;
    f32x4 pv0, pv1;

    // ---- prologue: stage tile 0 into buf 0 ----
    if (A_F32) {
        const float* ap = (const float*)Av + (size_t)arow * K + koA;
        pv0 = *(const f32x4*)ap; pv1 = *(const f32x4*)(ap + 4);
    } else {
        gld_lds16((const _Float16*)Av + (size_t)arow * K + koA, sA[0] + (size_t)(w * 64) * 8);
    }
    #pragma unroll
    for (int j = 0; j < 4; ++j)
        gld_lds16(Bt + (size_t)nrowB[j] * K + (j & 1) * 32 + kg * 8, sB[0] + (size_t)((w * 4 + j) * 64) * 8);
    if (A_F32) cvt_store<GELU>(sA[0] + (size_t)(w * 64 + lane) * 8, pv0, pv1);
    __syncthreads();

    int buf = 0;
    for (int t = 0; t < nt; ++t) {
        const int nxt = buf ^ 1;
        const bool more = (t + 1) < nt;
        if (more) {
            const int kb = (t + 1) << 6;
            if (A_F32) {
                const float* ap = (const float*)Av + (size_t)arow * K + kb + koA;
                pv0 = *(const f32x4*)ap; pv1 = *(const f32x4*)(ap + 4);
            } else {
                gld_lds16((const _Float16*)Av + (size_t)arow * K + kb + koA, sA[nxt] + (size_t)(w * 64) * 8);
            }
            #pragma unroll
            for (int j = 0; j < 4; ++j)
                gld_lds16(Bt + (size_t)nrowB[j] * K + kb + (j & 1) * 32 + kg * 8, sB[nxt] + (size_t)((w * 4 + j) * 64) * 8);
        }
        half8 af[2][2], bf[2][2];
        #pragma unroll
        for (int mi2 = 0; mi2 < 2; ++mi2)
            #pragma unroll
            for (int kk = 0; kk < 2; ++kk)
                af[mi2][kk] = *(const half8*)(sA[buf] + (size_t)((mi2 * 2 + kk) * 64 + lane) * 8);
        #pragma unroll
        for (int ni = 0; ni < 2; ++ni)
            #pragma unroll
            for (int kk = 0; kk < 2; ++kk)
                bf[ni][kk] = *(const half8*)(sB[buf] + (size_t)((w * 4 + ni * 2 + kk) * 64 + lane) * 8);
        #pragma unroll
        for (int mi2 = 0; mi2 < 2; ++mi2)
            #pragma unroll
            for (int ni = 0; ni < 2; ++ni)
                #pragma unroll
                for (int kk = 0; kk < 2; ++kk)
                    acc[mi2][ni] = __builtin_amdgcn_mfma_f32_16x16x32_f16(af[mi2][kk], bf[ni][kk], acc[mi2][ni], 0, 0, 0);
        if (more && A_F32) cvt_store<GELU>(sA[nxt] + (size_t)(w * 64 + lane) * 8, pv0, pv1);
        __syncthreads();
        buf = nxt;
    }

    float be = 0.f;
    if (MODE == 2) be = 1.0f / (1.0f + __expf(-gate[0]));
    #pragma unroll
    for (int mi2 = 0; mi2 < 2; ++mi2) {
        #pragma unroll
        for (int ni = 0; ni < 2; ++ni) {
            const int col = w * 32 + ni * 16 + rl;
            if (col >= N) continue;
            #pragma unroll
            for (int r = 0; r < 4; ++r) {
                const int row = bm + mi2 * 16 + kg * 4 + r;
                if (row >= M) continue;
                float val = acc[mi2][ni][r] + bias[col];
                if (MODE == 1) val = (val >= 0.f) ? val : 0.01f * val;
                if (MODE == 2) val = be * val + (1.f - be) * (float)Dh[(size_t)row * HDIM + col];
                C[(size_t)row * N + col] = (_Float16)val;
            }
        }
    }
}

// ---------------- fused two-relation per-dst softmax attention ----------------
// wave per dst; lane owns channel pair (2l, 2l+1); 4-edge unroll; no max-shift
// (alpha = p * q.k/sqrt(128), sigma ~0.5, |alpha| << 88 -> plain expf is f32-safe and
//  softmax is shift-invariant, so results match the max-subtracted reference)
__global__ __launch_bounds__(256) void attn2_kernel(
    const _Float16* __restrict__ qkv,
    const int* __restrict__ ptr0, const int* __restrict__ csr0,
    const int* __restrict__ ptr1, const int* __restrict__ csr1,
    const float* __restrict__ p0, const float* __restrict__ p1,
    float* __restrict__ att)
{
    const int w = (blockIdx.x * 256 + threadIdx.x) >> 6;
    if (w >= NNODES) return;
    const int lane = threadIdx.x & 63;
    half2v qh = *(const half2v*)(qkv + (size_t)w * 640 + (lane << 1));
    const float qx = (float)qh[0], qy = (float)qh[1];
    float ox = 0.f, oy = 0.f;
    #pragma unroll
    for (int r = 0; r < 2; ++r) {
        const int* ptrv = r ? ptr1 : ptr0;
        const int* csr  = r ? csr1 : csr0;
        const float scale = (r ? p1[0] : p0[0]) * 0.08838834764831845f; // 1/sqrt(128)
        const int start = ptrv[w], end = ptrv[w + 1];
        if (start == end) continue;
        const _Float16* tbl = qkv + 128 + 256 * r + (lane << 2);
        float denom = 0.f, ax = 0.f, ay = 0.f;
        int i = start;
        for (; i + 4 <= end; i += 4) {
            const int s0 = csr[i], s1 = csr[i + 1], s2 = csr[i + 2], s3 = csr[i + 3];
            half4 kv0 = *(const half4*)(tbl + (size_t)s0 * 640);
            half4 kv1 = *(const half4*)(tbl + (size_t)s1 * 640);
            half4 kv2 = *(const half4*)(tbl + (size_t)s2 * 640);
            half4 kv3 = *(const half4*)(tbl + (size_t)s3 * 640);
            float d0 = qx * (float)kv0[0] + qy * (float)kv0[1];
            float d1 = qx * (float)kv1[0] + qy * (float)kv1[1];
            float d2 = qx * (float)kv2[0] + qy * (float)kv2[1];
            float d3 = qx * (float)kv3[0] + qy * (float)kv3[1];
            #pragma unroll
            for (int o2 = 32; o2; o2 >>= 1) {
                d0 += __shfl_xor(d0, o2, 64);
                d1 += __shfl_xor(d1, o2, 64);
                d2 += __shfl_xor(d2, o2, 64);
                d3 += __shfl_xor(d3, o2, 64);
            }
            const float e0 = __expf(d0 * scale), e1 = __expf(d1 * scale);
            const float e2 = __expf(d2 * scale), e3 = __expf(d3 * scale);
            denom += (e0 + e1) + (e2 + e3);
            ax += e0 * (float)kv0[2] + e1 * (float)kv1[2] + e2 * (float)kv2[2] + e3 * (float)kv3[2];
            ay += e0 * (float)kv0[3] + e1 * (float)kv1[3] + e2 * (float)kv2[3] + e3 * (float)kv3[3];
        }
        for (; i < end; ++i) {
            const int s = csr[i];
            half4 kv = *(const half4*)(tbl + (size_t)s * 640);
            float d = qx * (float)kv[0] + qy * (float)kv[1];
            #pragma unroll
            for (int o2 = 32; o2; o2 >>= 1) d += __shfl_xor(d, o2, 64);
            const float e = __expf(d * scale);
            denom += e;
            ax += e * (float)kv[2];
            ay += e * (float)kv[3];
        }
        const float inv = 1.0f / denom;
        ox += ax * inv; oy += ay * inv;
    }
    *reinterpret_cast<float2*>(att + (size_t)w * HDIM + (lane << 1)) = make_float2(ox, oy);
}

// ---------------- tiny head tail: out[i,:2] = h[i,:64] @ Wo2 + bo2 ----------------
__global__ __launch_bounds__(256) void head2_kernel(const _Float16* __restrict__ h,
                                                    const float* __restrict__ Wo2,
                                                    const float* __restrict__ bo2,
                                                    float* __restrict__ out)
{
    int i = blockIdx.x * 256 + threadIdx.x;
    if (i >= NNODES) return;
    const _Float16* hp = h + (size_t)i * 64;
    float s0 = bo2[0], s1 = bo2[1];
    #pragma unroll
    for (int j0 = 0; j0 < 64; j0 += 8) {
        half8 hv = *(const half8*)(hp + j0);
        #pragma unroll
        for (int j = 0; j < 8; ++j) {
            float v = (float)hv[j];
            s0 += v * Wo2[2 * (j0 + j)];
            s1 += v * Wo2[2 * (j0 + j) + 1];
        }
    }
    out[2 * i] = s0;
    out[2 * i + 1] = s1;
}

// ---------------- launch ----------------

extern "C" void kernel_launch(void* const* d_in, const int* in_sizes, int n_in,
                              void* d_out, int out_size, void* d_ws, size_t ws_size,
                              hipStream_t stream)
{
    const float* features = (const float*)d_in[0];
    const int* ei0 = (const int*)d_in[1];
    const int* ei1 = (const int*)d_in[2];
    const float* W1 = (const float*)d_in[3];
    const float* b1 = (const float*)d_in[4];
    const float* Wk = (const float*)d_in[5];
    const float* bk = (const float*)d_in[6];
    const float* Wq = (const float*)d_in[7];
    const float* bq = (const float*)d_in[8];
    const float* Wv = (const float*)d_in[9];
    const float* bv = (const float*)d_in[10];
    const float* A0 = (const float*)d_in[11];
    const float* M0 = (const float*)d_in[12];
    const float* p0 = (const float*)d_in[13];
    const float* A1 = (const float*)d_in[14];
    const float* M1 = (const float*)d_in[15];
    const float* p1 = (const float*)d_in[16];
    const float* Wa = (const float*)d_in[17];
    const float* ba = (const float*)d_in[18];
    const float* skip = (const float*)d_in[19];
    const float* Wo1 = (const float*)d_in[20];
    const float* bo1 = (const float*)d_in[21];
    const float* Wo2 = (const float*)d_in[22];
    const float* bo2 = (const float*)d_in[23];
    (void)in_sizes; (void)n_in; (void)out_size; (void)ws_size;

    char* base = (char*)d_ws;
    size_t off = 0;
    auto alloc = [&](size_t bytes) { size_t r = off; off = (off + bytes + 255) & ~(size_t)255; return base + r; };

    _Float16* x0h  = (_Float16*)alloc((size_t)NNODES * HDIM * 2);
    _Float16* x1h  = (_Float16*)alloc((size_t)NNODES * HDIM * 2);
    _Float16* qkv  = (_Float16*)alloc((size_t)NNODES * 640 * 2);
    float*    att  = (float*)   alloc((size_t)NNODES * HDIM * 4);
    _Float16* hh   = (_Float16*)alloc((size_t)NNODES * 64 * 2);
    float* WkA[2]  = { (float*)alloc(65536), (float*)alloc(65536) };
    float* WvM[2]  = { (float*)alloc(65536), (float*)alloc(65536) };
    _Float16* WqkvT = (_Float16*)alloc(640 * 128 * 2);
    float*    bqkv  = (float*)   alloc(640 * 4);
    _Float16* W1T   = (_Float16*)alloc(128 * 768 * 2);
    _Float16* WaT   = (_Float16*)alloc(128 * 128 * 2);
    _Float16* Wo1T  = (_Float16*)alloc(64 * 128 * 2);
    int* deg[2]  = { (int*)alloc(NNODES * 4), (int*)alloc(NNODES * 4) };
    int* ptrv[2] = { (int*)alloc((NNODES + 1) * 4), (int*)alloc((NNODES + 1) * 4) };
    int* fill[2] = { (int*)alloc(NNODES * 4), (int*)alloc(NNODES * 4) };
    int* csr[2]  = { (int*)alloc(NEDGE * 4),  (int*)alloc(NEDGE * 4) };
    int* sums    = (int*)alloc(2 * 64 * 4);

    // ---- CSR build (edge structure shared by both layers) ----
    hipMemsetAsync(deg[0], 0, NNODES * 4, stream);
    hipMemsetAsync(deg[1], 0, NNODES * 4, stream);
    hipMemsetAsync(fill[0], 0, NNODES * 4, stream);
    hipMemsetAsync(fill[1], 0, NNODES * 4, stream);
    const int egrid = (NEDGE + 255) / 256;
    count2_kernel<<<dim3(egrid, 2), 256, 0, stream>>>(ei0, ei1, deg[0], deg[1]);
    scan1_kernel<<<dim3(NSB, 2), 1024, 0, stream>>>(deg[0], deg[1], ptrv[0], ptrv[1], sums);
    scan2_kernel<<<2, 64, 0, stream>>>(sums, ptrv[0], ptrv[1]);
    scan3_kernel<<<dim3(NSB, 2), 1024, 0, stream>>>(sums, ptrv[0], ptrv[1]);
    scatter2_kernel<<<dim3(egrid, 2), 256, 0, stream>>>(ei0, ei1, ptrv[0], ptrv[1],
                                                        fill[0], fill[1], csr[0], csr[1]);

    // ---- combined relation weights + biases ----
    gemm_cmb_kernel<<<dim3(2, 2, 4), 256, 0, stream>>>(Wk, Wv, A0, M0, A1, M1,
                                                       WkA[0], WvM[0], WkA[1], WvM[1]);
    bias_cmb_kernel<<<4, 128, 0, stream>>>(bk, bv, A0, M0, A1, M1, bqkv);

    // ---- pack fp16 transposed weights ----
    pack_qkvT<<<640, 128, 0, stream>>>(Wq, WkA[0], WvM[0], WkA[1], WvM[1], bq, WqkvT, bqkv);
    transpose_h<<<128, 768, 0, stream>>>(W1, W1T, 768, 128);
    transpose_h<<<128, 128, 0, stream>>>(Wa, WaT, 128, 128);
    transpose_h<<<64, 128, 0, stream>>>(Wo1, Wo1T, 128, 64);

    const int MBLK = (NNODES + 127) / 128;   // 391
    const int MBLK32 = (NNODES + 31) / 32;   // 1563

    // ---- x0 = leaky(features @ W1 + b1) -> fp16 ----
    gemm_h32<1, true, false><<<MBLK32, 256, 0, stream>>>(
        features, W1T, b1, nullptr, nullptr, x0h, NNODES, HDIM, FIN);

    // ---- two HGT layers ----
    _Float16* xin = x0h;
    _Float16* xout = x1h;
    for (int layer = 0; layer < 2; ++layer) {
        gemm_h<0, false, false><<<dim3(MBLK, 5), 256, 0, stream>>>(
            xin, WqkvT, bqkv, nullptr, nullptr, qkv, NNODES, 640, HDIM);
        attn2_kernel<<<(NNODES * 64 + 255) / 256, 256, 0, stream>>>(
            qkv, ptrv[0], csr[0], ptrv[1], csr[1], p0, p1, att);
        gemm_h32<2, true, true><<<MBLK32, 256, 0, stream>>>(
            att, WaT, ba, xin, skip, xout, NNODES, HDIM, HDIM);
        _Float16* tmp = xin; xin = xout; xout = tmp;
    }

    // ---- head ----
    gemm_h32<1, false, false><<<MBLK32, 256, 0, stream>>>(
        xin, Wo1T, bo1, nullptr, nullptr, hh, NNODES, 64, HDIM);
    head2_kernel<<<(NNODES + 255) / 256, 256, 0, stream>>>(hh, Wo2, bo2, (float*)d_out);
}